// Round 6
// baseline (978.784 us; speedup 1.0000x reference)
//
#include <hip/hip_runtime.h>

#define BB  512
#define SS  100
#define DD  512
#define DFF 256
#define HIDN 230
#define LDA 520   // padded LDS row stride (bf16 elems)

typedef unsigned short u16;
typedef unsigned int   u32;
typedef __attribute__((ext_vector_type(8))) short v8s;  // 8 bf16 (4 VGPRs) MFMA frag
typedef __attribute__((ext_vector_type(4))) float v4f;  // 4 f32 accum

__device__ __forceinline__ float b2f(u16 u){
  union { u32 i; float f; } v; v.i = ((u32)u) << 16; return v.f;
}
__device__ __forceinline__ u16 f2b(float f){
  union { float f; u32 i; } v; v.f = f;
  u32 r = (v.i + 0x7fffu + ((v.i >> 16) & 1u)) >> 16;  // RNE
  return (u16)r;
}
__device__ __forceinline__ float rsum16(float s){
  #pragma unroll
  for (int o = 1; o < 16; o <<= 1) s += __shfl_xor(s, o, 64);
  return s;
}

// async global -> LDS, 16B per lane.  LDS dest is WAVE-UNIFORM base (+lane*16 implicit);
// global src is per-lane.
__device__ __forceinline__ void gl16(const u16* g, u16* l){
  __builtin_amdgcn_global_load_lds(
      (const __attribute__((address_space(1))) void*)g,
      (__attribute__((address_space(3))) void*)l, 16, 0, 0);
}

// ---- LDS-staged GEMM: 2-phase double-buffered k-loop (T3 minimum template) ----
// Packed weights: tile t, k-chunk kc, lane l -> W + t*16*K + kc*512 + l*8.
// Per phase (sub-panel nh, k-chunk kc): 16 tiles (16KB) live in Bb[par];
// wave wid owns tile slots s0=wid*4 .. s0+3.  acc[nh*4+i] = tile (nh*16+s0+i).
template<int K, int NH>
__device__ __forceinline__ void gemm_lds(const u16 (*Asrc)[LDA], const u16* __restrict__ W,
                                         u16 (*Bb)[8192], int s0, int lane, int m, int q,
                                         v4f* acc){
  constexpr int NC = K / 32;   // NC even (8 or 16) -> buffer parity == kc&1
  // prologue: stage phase (0,0) into buf 0
  {
    const u16* src = W + (size_t)s0*16*K + lane*8;
    u16* dst = Bb[0] + s0*512;
    #pragma unroll
    for (int i = 0; i < 4; i++) gl16(src + (size_t)i*16*K, dst + i*512);
  }
  __syncthreads();   // drains vmcnt(0): buf0 ready
  #pragma unroll
  for (int nh = 0; nh < NH; nh++){
    for (int kc = 0; kc < NC; kc++){
      // stage next phase into the other buffer (issued BEFORE compute)
      int nkc = kc + 1, nnh = nh;
      if (nkc == NC){ nkc = 0; nnh++; }
      if (nnh < NH){
        const u16* src = W + (size_t)(nnh*16 + s0)*16*K + nkc*512 + lane*8;
        u16* dst = Bb[(kc + 1) & 1] + s0*512;
        #pragma unroll
        for (int i = 0; i < 4; i++) gl16(src + (size_t)i*16*K, dst + i*512);
      }
      // compute current phase from buf[kc&1]
      v8s a = *(const v8s*)(&Asrc[m][kc*32 + q*8]);
      const u16* bp = Bb[kc & 1] + s0*512 + lane*8;
      #pragma unroll
      for (int i = 0; i < 4; i++){
        v8s b = *(const v8s*)(bp + i*512);
        acc[nh*4 + i] = __builtin_amdgcn_mfma_f32_16x16x32_bf16(a, b, acc[nh*4 + i], 0, 0, 0);
      }
      __syncthreads();   // next buffer staged + all reads of current done
    }
  }
}

// custom LN (unbiased std, eps added to std) over 512 cols; 16 threads per row.
template<bool ADDX>
__device__ __forceinline__ void ln_custom_pass(int lrow, int lc,
    const u16 (*src)[LDA], u16 (*dst)[LDA], const u32* xp,
    const u16* __restrict__ g, const u16* __restrict__ bb)
{
  float v[32]; float s = 0.f;
  #pragma unroll
  for (int j = 0; j < 32; j++){ int col = lc + j*16; float x = b2f(src[lrow][col]); v[j] = x; s += x; }
  s = rsum16(s);
  float mean = s * (1.0f/512.0f);
  float vs = 0.f;
  #pragma unroll
  for (int j = 0; j < 32; j++){ float d = v[j] - mean; vs += d*d; }
  vs = rsum16(vs);
  float inv = 1.0f / (sqrtf(vs * (1.0f/511.0f)) + 1e-6f);
  #pragma unroll
  for (int j = 0; j < 32; j++){
    int col = lc + j*16;
    float r = b2f(g[col]) * (v[j] - mean) * inv + b2f(bb[col]);
    if (ADDX){
      u32 p = xp[j >> 1];
      u16 xu = (j & 1) ? (u16)(p >> 16) : (u16)(p & 0xffffu);
      r += b2f(xu);
    }
    dst[lrow][col] = f2b(r);
  }
}

// ---------------- k_pre: cvt (f32 -> packed bf16)  +  per-batch attention collapse ----
#define NSEG 20
struct CvtArgs {
  const float* src[NSEG];
  u16* dst;
  int off[NSEG];   // OUTPUT offsets (elements)
  int n[NSEG];     // OUTPUT lengths
  int ncs[6];      // log2(K/32) for the 6 matrices
  int nin[6];      // valid input N (cols) for the 6 matrices
};
__global__ __launch_bounds__(512) void k_pre(CvtArgs a,
    const float* __restrict__ inp, const int* __restrict__ mask,
    const float* __restrict__ wv, const float* __restrict__ bv,
    const float* __restrict__ fcw, const float* __restrict__ fcb,
    float* __restrict__ a_m, float* __restrict__ a_u)
{
  // ---- part 1: weight conversion (grid-stride, independent of part 2) ----
  {
    int total = a.off[NSEG-1] + a.n[NSEG-1];
    for (int i = blockIdx.x*blockDim.x + threadIdx.x; i < total; i += gridDim.x*blockDim.x){
      int s = 0;
      #pragma unroll
      for (int j = 1; j < NSEG; j++) if (i >= a.off[j]) s = j;
      int o = i - a.off[s];
      if (s < 6){
        int j  = o & 7;
        int l  = (o >> 3) & 63;
        int m  = l & 15, q = l >> 4;
        int rest = o >> 9;
        int ncs = a.ncs[s];
        int kc = rest & ((1 << ncs) - 1);
        int t  = rest >> ncs;
        int col = t*16 + m;
        int k   = kc*32 + q*8 + j;
        int K   = 32 << ncs;
        float v = (col < a.nin[s]) ? a.src[s][(size_t)col*K + k] : 0.f;
        a.dst[i] = f2b(v);
      } else {
        a.dst[i] = f2b(a.src[s][o]);
      }
    }
  }
  // ---- part 2: attention collapse (one block per batch) ----
  __shared__ float sia[DD], sim[DD], cm[DD], cu[DD];
  __shared__ int smask[SS];
  const int b = blockIdx.x, t = threadIdx.x;
  const int lane = t & 63, w8 = t >> 6;   // 8 waves
  if (t < SS) smask[t] = mask[b*SS + t];
  __syncthreads();
  const float* base = inp + (size_t)b * SS * DD;
  float aa = 0.f, am = 0.f; int n = 0;
  for (int s = 0; s < SS; s++){
    float x = base[s*DD + t];
    int mk = smask[s];
    aa += x; n += (mk != 0); if (mk) am += x;
  }
  sia[t] = aa; sim[t] = am;
  __syncthreads();
  const float e0 = expf(1e-8f - 1.0f);
  const float denom = (float)n + (float)(SS - n) * e0;
  const float p1 = 1.0f / denom, p0 = e0 / denom;
  {
    float s_a[8], s_m[8];
    #pragma unroll
    for (int j = 0; j < 8; j++){ s_a[j] = sia[lane*8 + j]; s_m[j] = sim[lane*8 + j]; }
    for (int rr = 0; rr < 64; rr++){
      int d = w8*64 + rr;
      const float4* wr = (const float4*)(wv + (size_t)d * DD + lane*8);
      float4 wA = wr[0], wB = wr[1];
      float sva = wA.x*s_a[0] + wA.y*s_a[1] + wA.z*s_a[2] + wA.w*s_a[3]
                + wB.x*s_a[4] + wB.y*s_a[5] + wB.z*s_a[6] + wB.w*s_a[7];
      float svm = wA.x*s_m[0] + wA.y*s_m[1] + wA.z*s_m[2] + wA.w*s_m[3]
                + wB.x*s_m[4] + wB.y*s_m[5] + wB.z*s_m[6] + wB.w*s_m[7];
      #pragma unroll
      for (int o = 1; o < 64; o <<= 1){ sva += __shfl_xor(sva, o, 64); svm += __shfl_xor(svm, o, 64); }
      if (lane == 0){
        float bvd = bv[d];
        sva += (float)SS * bvd;
        svm += (float)n  * bvd;
        cm[d] = p1*svm + p0*(sva - svm);
        cu[d] = sva * (1.0f/(float)SS);
      }
    }
  }
  __syncthreads();
  {
    float c_m[8], c_u[8];
    #pragma unroll
    for (int j = 0; j < 8; j++){ c_m[j] = cm[lane*8 + j]; c_u[j] = cu[lane*8 + j]; }
    for (int rr = 0; rr < 64; rr++){
      int d = w8*64 + rr;
      const float4* fr = (const float4*)(fcw + (size_t)d * DD + lane*8);
      float4 wA = fr[0], wB = fr[1];
      float xm = wA.x*c_m[0] + wA.y*c_m[1] + wA.z*c_m[2] + wA.w*c_m[3]
               + wB.x*c_m[4] + wB.y*c_m[5] + wB.z*c_m[6] + wB.w*c_m[7];
      float xu = wA.x*c_u[0] + wA.y*c_u[1] + wA.z*c_u[2] + wA.w*c_u[3]
               + wB.x*c_u[4] + wB.y*c_u[5] + wB.z*c_u[6] + wB.w*c_u[7];
      #pragma unroll
      for (int o = 1; o < 64; o <<= 1){ xm += __shfl_xor(xm, o, 64); xu += __shfl_xor(xu, o, 64); }
      if (lane == 0){
        float fb = fcb[d];
        a_m[(size_t)b*DD + d] = xm + fb;
        a_u[(size_t)b*DD + d] = xu + fb;
      }
    }
  }
}

// ---------------- K2: fused per-row chain, 16 rows/block, LDS-staged GEMMs ----------------
__global__ __launch_bounds__(256, 2) void k_main(
    const float* __restrict__ inp, const int* __restrict__ mask,
    const u16* __restrict__ lnm_g, const u16* __restrict__ lnm_b,
    const u16* __restrict__ w1,   const u16* __restrict__ b1,
    const u16* __restrict__ w2,   const u16* __restrict__ b2,
    const u16* __restrict__ lpc_w, const u16* __restrict__ lpc_b,
    const u16* __restrict__ lnc_g, const u16* __restrict__ lnc_b,
    const u16* __restrict__ pwf_w, const u16* __restrict__ pwf_b,
    const u16* __restrict__ lpi_w, const u16* __restrict__ lpi_b,
    const u16* __restrict__ lni_g, const u16* __restrict__ lni_b,
    const u16* __restrict__ lnf_g, const u16* __restrict__ lnf_b,
    const u16* __restrict__ mlpf_w, const u16* __restrict__ mlpf_b,
    const float* __restrict__ a_m, const float* __restrict__ a_u,
    float* __restrict__ out)
{
  __shared__ __align__(16) u16 A[16][LDA];   // GEMM A operand / LN outputs
  __shared__ __align__(16) u16 O[16][LDA];   // x staging, GEMM outputs / pre-LN staging
  __shared__ __align__(16) u16 Bb[2][8192];  // double-buffered B k-chunk (2 x 16KB)
  __shared__ int marr[16];

  const int tid  = threadIdx.x;
  const int lane = tid & 63, wid = tid >> 6;  // 4 waves
  const int m = lane & 15, q = lane >> 4;
  const int s0 = wid * 4;                     // this wave's 4 tile slots
  const int r0 = blockIdx.x * 16;
  const int lrow = tid >> 4, lc = tid & 15;   // LN pass: 16 threads per row

  // ---- load 16 inp rows (f32 -> bf16) into O ----
  {
    if (tid < 16) marr[tid] = mask[r0 + tid];
    float4 va[4], vb[4];
    #pragma unroll
    for (int c = 0; c < 4; c++){
      int e = c*2048 + tid*8;                 // element index in [0, 8192)
      int row = e >> 9, col = e & 511;
      const float4* p = (const float4*)(inp + (size_t)(r0 + row) * DD + col);
      va[c] = p[0]; vb[c] = p[1];
    }
    #pragma unroll
    for (int c = 0; c < 4; c++){
      int e = c*2048 + tid*8;
      int row = e >> 9, col = e & 511;
      uint4 o;
      o.x = (u32)f2b(va[c].x) | ((u32)f2b(va[c].y) << 16);
      o.y = (u32)f2b(va[c].z) | ((u32)f2b(va[c].w) << 16);
      o.z = (u32)f2b(vb[c].x) | ((u32)f2b(vb[c].y) << 16);
      o.w = (u32)f2b(vb[c].z) | ((u32)f2b(vb[c].w) << 16);
      *(uint4*)&O[row][col] = o;
    }
  }
  __syncthreads();

  // ---- LN1 (torch LN): mha = LN(a_sel + x) -> A ; capture x into regs (packed bf16) ----
  u32 xp[16];
  {
    int Rg = r0 + lrow;
    int bi = Rg / SS;
    const float* asel = (marr[lrow] ? a_m : a_u) + (size_t)bi * DD;
    float v[32]; float s = 0.f;
    #pragma unroll
    for (int j = 0; j < 32; j++){
      int col = lc + j*16;
      u16 xu = O[lrow][col];
      if ((j & 1) == 0) xp[j >> 1] = (u32)xu;
      else              xp[j >> 1] |= ((u32)xu << 16);
      float x = asel[col] + b2f(xu);
      v[j] = x; s += x;
    }
    s = rsum16(s);
    float mean = s * (1.0f/512.0f);
    float vs = 0.f;
    #pragma unroll
    for (int j = 0; j < 32; j++){ float d = v[j] - mean; vs += d*d; }
    vs = rsum16(vs);
    float inv = 1.0f / sqrtf(vs * (1.0f/512.0f) + 1e-5f);
    #pragma unroll
    for (int j = 0; j < 32; j++){
      int col = lc + j*16;
      float r = b2f(lnm_g[col]) * (v[j] - mean) * inv + b2f(lnm_b[col]);
      A[lrow][col] = f2b(r);
    }
  }
  __syncthreads();

  // ---- GEMM1: h1 = relu(mha @ w1^T + b1) -> O[:,0:256] ----
  {
    v4f acc[4];
    #pragma unroll
    for (int i = 0; i < 4; i++) acc[i] = (v4f){0.f,0.f,0.f,0.f};
    gemm_lds<512,1>(A, w1, Bb, s0, lane, m, q, acc);
    #pragma unroll
    for (int i = 0; i < 4; i++){
      int col = (s0 + i)*16 + m;
      float bias = b2f(b1[col]);
      #pragma unroll
      for (int r = 0; r < 4; r++){
        float val = acc[i][r] + bias;
        O[q*4+r][col] = f2b(val > 0.f ? val : 0.f);
      }
    }
  }
  __syncthreads();

  // ---- GEMM2: ffn = h1 @ w2^T + b2 ; (ffn + mha residual) -> O ----
  {
    v4f acc[8];
    #pragma unroll
    for (int i = 0; i < 8; i++) acc[i] = (v4f){0.f,0.f,0.f,0.f};
    gemm_lds<256,2>(O, w2, Bb, s0, lane, m, q, acc);   // ends with barrier: all reads of O done
    #pragma unroll
    for (int nh = 0; nh < 2; nh++)
      #pragma unroll
      for (int i = 0; i < 4; i++){
        int col = nh*256 + (s0 + i)*16 + m;
        float bias = b2f(b2[col]);
        #pragma unroll
        for (int r = 0; r < 4; r++){
          int row = q*4 + r;
          O[row][col] = f2b(acc[nh*4+i][r] + bias + b2f(A[row][col]));
        }
      }
  }
  __syncthreads();

  // ---- LN2 (custom, lni): ctx2 = LNc(ffn+mha); y = ctx2 + x -> A ----
  ln_custom_pass<true>(lrow, lc, O, A, xp, lni_g, lni_b);
  __syncthreads();

  // ---- GEMM3: z = y @ lpc_w^T + 2*lpc_b -> O ----
  {
    v4f acc[8];
    #pragma unroll
    for (int i = 0; i < 8; i++) acc[i] = (v4f){0.f,0.f,0.f,0.f};
    gemm_lds<512,2>(A, lpc_w, Bb, s0, lane, m, q, acc);
    #pragma unroll
    for (int nh = 0; nh < 2; nh++)
      #pragma unroll
      for (int i = 0; i < 4; i++){
        int col = nh*256 + (s0 + i)*16 + m;
        float bias = 2.0f * b2f(lpc_b[col]);
        #pragma unroll
        for (int r = 0; r < 4; r++) O[q*4+r][col] = f2b(acc[nh*4+i][r] + bias);
      }
  }
  __syncthreads();

  // ---- LN3 (custom, lnc): res_inp = LNc(z) -> A ----
  ln_custom_pass<false>(lrow, lc, O, A, nullptr, lnc_g, lnc_b);
  __syncthreads();

  // ---- GEMM4: h2 = relu(res_inp @ pwf^T + pwf_b) -> O[:,0:256] ----
  {
    v4f acc[4];
    #pragma unroll
    for (int i = 0; i < 4; i++) acc[i] = (v4f){0.f,0.f,0.f,0.f};
    gemm_lds<512,1>(A, pwf_w, Bb, s0, lane, m, q, acc);
    #pragma unroll
    for (int i = 0; i < 4; i++){
      int col = (s0 + i)*16 + m;
      float bias = b2f(pwf_b[col]);
      #pragma unroll
      for (int r = 0; r < 4; r++){
        float val = acc[i][r] + bias;
        O[q*4+r][col] = f2b(val > 0.f ? val : 0.f);
      }
    }
  }
  __syncthreads();

  // ---- GEMM5: rv = h2 @ lpi^T + lpi_b ; (rv + res_inp residual) -> O ----
  {
    v4f acc[8];
    #pragma unroll
    for (int i = 0; i < 8; i++) acc[i] = (v4f){0.f,0.f,0.f,0.f};
    gemm_lds<256,2>(O, lpi_w, Bb, s0, lane, m, q, acc);  // ends with barrier
    #pragma unroll
    for (int nh = 0; nh < 2; nh++)
      #pragma unroll
      for (int i = 0; i < 4; i++){
        int col = nh*256 + (s0 + i)*16 + m;
        float bias = b2f(lpi_b[col]);
        #pragma unroll
        for (int r = 0; r < 4; r++){
          int row = q*4 + r;
          O[row][col] = f2b(acc[nh*4+i][r] + bias + b2f(A[row][col]));
        }
      }
  }
  __syncthreads();

  // ---- LN4 (custom, lnf): res = LNc(rv+res_inp) -> A ----
  ln_custom_pass<false>(lrow, lc, O, A, nullptr, lnf_g, lnf_b);
  __syncthreads();

  // ---- GEMM6: out = res @ mlpf^T + mlpf_b  (packed 256 cols, zeros >=230) ----
  {
    v4f acc[4];
    #pragma unroll
    for (int i = 0; i < 4; i++) acc[i] = (v4f){0.f,0.f,0.f,0.f};
    gemm_lds<512,1>(A, mlpf_w, Bb, s0, lane, m, q, acc);
    #pragma unroll
    for (int i = 0; i < 4; i++){
      int col = (s0 + i)*16 + m;
      if (col < HIDN){
        float bias = b2f(mlpf_b[col]);
        #pragma unroll
        for (int r = 0; r < 4; r++){
          int row = q*4 + r;
          out[(size_t)(r0 + row)*HIDN + col] = acc[i][r] + bias;   // float32 output
        }
      }
    }
  }
}

extern "C" void kernel_launch(void* const* d_in, const int* in_sizes, int n_in,
                              void* d_out, int out_size, void* d_ws, size_t ws_size,
                              hipStream_t stream)
{
  const float* inp    = (const float*)d_in[0];
  const int*   mask   = (const int*)d_in[1];
  // d_in[2] = gate: dead computation in the reference
  const float* wv     = (const float*)d_in[3];
  const float* bv     = (const float*)d_in[4];
  const float* fc_w   = (const float*)d_in[5];
  const float* fc_b   = (const float*)d_in[6];

  // ws layout: a_m f32[512*512] | a_u f32[512*512] | bf16 packed weights/vectors
  float* a_m = (float*)d_ws;
  float* a_u = a_m + (size_t)BB * DD;
  u16* bfb = (u16*)((char*)d_ws + 2u * BB * DD * sizeof(float));

  // packed bf16 region offsets (elements)
  const int OW1   = 0;                       // 256x512 packed
  const int OW2   = OW1   + DFF*DD;          // 512x256 packed
  const int OLPC  = OW2   + DD*DFF;          // 512x512 packed
  const int OPWF  = OLPC  + DD*DD;           // 256x512 packed
  const int OLPI  = OPWF  + DFF*DD;          // 512x256 packed
  const int OMLPF = OLPI  + DD*DFF;          // 256x512 packed (cols >=230 zero)
  int voff = OMLPF + 256*DD;
  const int OLNMG = voff; voff += DD;
  const int OLNMB = voff; voff += DD;
  const int OB1   = voff; voff += DFF;
  const int OB2   = voff; voff += DD;
  const int OLPCB = voff; voff += DD;
  const int OLNCG = voff; voff += DD;
  const int OLNCB = voff; voff += DD;
  const int OPWFB = voff; voff += DFF;
  const int OLPIB = voff; voff += DD;
  const int OLNIG = voff; voff += DD;
  const int OLNIB = voff; voff += DD;
  const int OLNFG = voff; voff += DD;
  const int OLNFB = voff; voff += DD;
  const int OMLPFB = voff; voff += HIDN;

  CvtArgs ca;
  const int srcidx[NSEG] = {9, 11, 13, 17, 19, 25,      // w1,w2,lpc_w,pwf_w,lpi_w,mlpf_w
                            7, 8, 10, 12, 14, 15, 16, 18, 20, 21, 22, 23, 24, 26};
  const int offs[NSEG]   = {OW1, OW2, OLPC, OPWF, OLPI, OMLPF,
                            OLNMG, OLNMB, OB1, OB2, OLPCB, OLNCG, OLNCB, OPWFB,
                            OLPIB, OLNIG, OLNIB, OLNFG, OLNFB, OMLPFB};
  const int lens[NSEG]   = {DFF*DD, DD*DFF, DD*DD, DFF*DD, DD*DFF, 256*DD,
                            DD, DD, DFF, DD, DD, DD, DD, DFF, DD, DD, DD, DD, DD, HIDN};
  const int ncss[6] = {4, 3, 4, 4, 3, 4};        // log2(K/32): K=512 -> 4, K=256 -> 3
  const int nins[6] = {DFF, DD, DD, DFF, DD, HIDN};
  for (int i = 0; i < NSEG; i++){
    ca.src[i] = (const float*)d_in[srcidx[i]];
    ca.off[i] = offs[i];
    ca.n[i]   = lens[i];
  }
  for (int i = 0; i < 6; i++){ ca.ncs[i] = ncss[i]; ca.nin[i] = nins[i]; }
  ca.dst = bfb;

  k_pre<<<BB, 512, 0, stream>>>(ca, inp, mask, wv, bv, fc_w, fc_b, a_m, a_u);
  k_main<<<(BB*SS)/16, 256, 0, stream>>>(inp, mask,
      bfb + OLNMG, bfb + OLNMB,
      bfb + OW1,   bfb + OB1,
      bfb + OW2,   bfb + OB2,
      bfb + OLPC,  bfb + OLPCB,
      bfb + OLNCG, bfb + OLNCB,
      bfb + OPWF,  bfb + OPWFB,
      bfb + OLPI,  bfb + OLPIB,
      bfb + OLNIG, bfb + OLNIB,
      bfb + OLNFG, bfb + OLNFB,
      bfb + OMLPF, bfb + OMLPFB,
      a_m, a_u, (float*)d_out);
}

// Round 7
// 540.270 us; speedup vs baseline: 1.8117x; 1.8117x over previous
//
#include <hip/hip_runtime.h>

#define BB  512
#define SS  100
#define DD  512
#define DFF 256
#define HIDN 230
#define LDA 520   // padded LDS row stride (bf16 elems); 1040B = 65*16 keeps b128 alignment

typedef unsigned short u16;
typedef unsigned int   u32;
typedef __attribute__((ext_vector_type(8))) short v8s;  // 8 bf16 (4 VGPRs) MFMA frag
typedef __attribute__((ext_vector_type(4))) float v4f;  // 4 f32 accum

__device__ __forceinline__ float b2f(u16 u){
  union { u32 i; float f; } v; v.i = ((u32)u) << 16; return v.f;
}
__device__ __forceinline__ u16 f2b(float f){
  union { float f; u32 i; } v; v.f = f;
  u32 r = (v.i + 0x7fffu + ((v.i >> 16) & 1u)) >> 16;  // RNE
  return (u16)r;
}
__device__ __forceinline__ float rsum16(float s){
  #pragma unroll
  for (int o = 1; o < 16; o <<= 1) s += __shfl_xor(s, o, 64);
  return s;
}

// ---- M=64 register-path GEMM: 4 M-tiles x NT N-tiles per wave, 2-deep prefetch ----
// Packed weights: tile t, k-chunk kc, lane l -> W + t*16*K + kc*512 + l*8.
// Wave w owns N-tiles {w + 16*j}, j=0..NT-1  (j step = 16 tiles = 256*K elems).
// acc[mt][j]: M-tile mt (rows mt*16 + q*4+0..3), N-tile (w+16j) (col (w+16j)*16+m).
template<int K, int NT>
__device__ __forceinline__ void mm64(const u16 (*Asrc)[LDA], const u16* __restrict__ W,
                                     int w, int lane, int m, int q, v4f (*acc)[NT]){
  constexpr int NC = K / 32;
  const u16* b0 = W + (size_t)w*16*K + lane*8;
  v8s a[4], b[NT];
  #pragma unroll
  for (int mt = 0; mt < 4; mt++) a[mt] = *(const v8s*)(&Asrc[mt*16 + m][q*8]);
  #pragma unroll
  for (int j = 0; j < NT; j++)  b[j]  = *(const v8s*)(b0 + (size_t)j*256*K);
  #pragma unroll
  for (int kc = 0; kc < NC; kc++){
    v8s an[4], bn[NT];
    if (kc + 1 < NC){
      #pragma unroll
      for (int j = 0; j < NT; j++)
        bn[j] = *(const v8s*)(b0 + (size_t)j*256*K + (kc+1)*512);
      #pragma unroll
      for (int mt = 0; mt < 4; mt++)
        an[mt] = *(const v8s*)(&Asrc[mt*16 + m][(kc+1)*32 + q*8]);
    } else {
      #pragma unroll
      for (int j = 0; j < NT; j++) bn[j] = b[j];
      #pragma unroll
      for (int mt = 0; mt < 4; mt++) an[mt] = a[mt];
    }
    #pragma unroll
    for (int j = 0; j < NT; j++)
      #pragma unroll
      for (int mt = 0; mt < 4; mt++)
        acc[mt][j] = __builtin_amdgcn_mfma_f32_16x16x32_bf16(a[mt], b[j], acc[mt][j], 0, 0, 0);
    #pragma unroll
    for (int j = 0; j < NT; j++) b[j] = bn[j];
    #pragma unroll
    for (int mt = 0; mt < 4; mt++) a[mt] = an[mt];
  }
}

// custom LN (unbiased std, eps added to std) over 512 cols; 16 threads per row.
template<bool ADDX>
__device__ __forceinline__ void ln_custom_pass(int lrow, int lc,
    const u16 (*src)[LDA], u16 (*dst)[LDA], const u32* xp,
    const u16* __restrict__ g, const u16* __restrict__ bb)
{
  float v[32]; float s = 0.f;
  #pragma unroll
  for (int j = 0; j < 32; j++){ int col = lc + j*16; float x = b2f(src[lrow][col]); v[j] = x; s += x; }
  s = rsum16(s);
  float mean = s * (1.0f/512.0f);
  float vs = 0.f;
  #pragma unroll
  for (int j = 0; j < 32; j++){ float d = v[j] - mean; vs += d*d; }
  vs = rsum16(vs);
  float inv = 1.0f / (sqrtf(vs * (1.0f/511.0f)) + 1e-6f);
  #pragma unroll
  for (int j = 0; j < 32; j++){
    int col = lc + j*16;
    float r = b2f(g[col]) * (v[j] - mean) * inv + b2f(bb[col]);
    if (ADDX){
      u32 p = xp[j >> 1];
      u16 xu = (j & 1) ? (u16)(p >> 16) : (u16)(p & 0xffffu);
      r += b2f(xu);
    }
    dst[lrow][col] = f2b(r);
  }
}

// ---------------- k_pre: cvt (f32 -> packed bf16)  +  per-batch attention collapse ----
#define NSEG 20
struct CvtArgs {
  const float* src[NSEG];
  u16* dst;
  int off[NSEG];   // OUTPUT offsets (elements)
  int n[NSEG];     // OUTPUT lengths
  int ncs[6];      // log2(K/32) for the 6 matrices
  int nin[6];      // valid input N (cols) for the 6 matrices
};
__global__ __launch_bounds__(512) void k_pre(CvtArgs a,
    const float* __restrict__ inp, const int* __restrict__ mask,
    const float* __restrict__ wv, const float* __restrict__ bv,
    const float* __restrict__ fcw, const float* __restrict__ fcb,
    float* __restrict__ a_m, float* __restrict__ a_u)
{
  // ---- part 1: weight conversion (grid-stride) ----
  {
    int total = a.off[NSEG-1] + a.n[NSEG-1];
    for (int i = blockIdx.x*blockDim.x + threadIdx.x; i < total; i += gridDim.x*blockDim.x){
      int s = 0;
      #pragma unroll
      for (int j = 1; j < NSEG; j++) if (i >= a.off[j]) s = j;
      int o = i - a.off[s];
      if (s < 6){
        int j  = o & 7;
        int l  = (o >> 3) & 63;
        int m  = l & 15, q = l >> 4;
        int rest = o >> 9;
        int ncs = a.ncs[s];
        int kc = rest & ((1 << ncs) - 1);
        int t  = rest >> ncs;
        int col = t*16 + m;
        int k   = kc*32 + q*8 + j;
        int K   = 32 << ncs;
        float v = (col < a.nin[s]) ? a.src[s][(size_t)col*K + k] : 0.f;
        a.dst[i] = f2b(v);
      } else {
        a.dst[i] = f2b(a.src[s][o]);
      }
    }
  }
  // ---- part 2: attention collapse (one block per batch) ----
  __shared__ float sia[DD], sim[DD], cm[DD], cu[DD];
  __shared__ int smask[SS];
  const int b = blockIdx.x, t = threadIdx.x;
  const int lane = t & 63, w8 = t >> 6;   // 8 waves
  if (t < SS) smask[t] = mask[b*SS + t];
  __syncthreads();
  const float* base = inp + (size_t)b * SS * DD;
  float aa = 0.f, am = 0.f; int n = 0;
  for (int s = 0; s < SS; s++){
    float x = base[s*DD + t];
    int mk = smask[s];
    aa += x; n += (mk != 0); if (mk) am += x;
  }
  sia[t] = aa; sim[t] = am;
  __syncthreads();
  const float e0 = expf(1e-8f - 1.0f);
  const float denom = (float)n + (float)(SS - n) * e0;
  const float p1 = 1.0f / denom, p0 = e0 / denom;
  {
    float s_a[8], s_m[8];
    #pragma unroll
    for (int j = 0; j < 8; j++){ s_a[j] = sia[lane*8 + j]; s_m[j] = sim[lane*8 + j]; }
    for (int rr = 0; rr < 64; rr++){
      int d = w8*64 + rr;
      const float4* wr = (const float4*)(wv + (size_t)d * DD + lane*8);
      float4 wA = wr[0], wB = wr[1];
      float sva = wA.x*s_a[0] + wA.y*s_a[1] + wA.z*s_a[2] + wA.w*s_a[3]
                + wB.x*s_a[4] + wB.y*s_a[5] + wB.z*s_a[6] + wB.w*s_a[7];
      float svm = wA.x*s_m[0] + wA.y*s_m[1] + wA.z*s_m[2] + wA.w*s_m[3]
                + wB.x*s_m[4] + wB.y*s_m[5] + wB.z*s_m[6] + wB.w*s_m[7];
      #pragma unroll
      for (int o = 1; o < 64; o <<= 1){ sva += __shfl_xor(sva, o, 64); svm += __shfl_xor(svm, o, 64); }
      if (lane == 0){
        float bvd = bv[d];
        sva += (float)SS * bvd;
        svm += (float)n  * bvd;
        cm[d] = p1*svm + p0*(sva - svm);
        cu[d] = sva * (1.0f/(float)SS);
      }
    }
  }
  __syncthreads();
  {
    float c_m[8], c_u[8];
    #pragma unroll
    for (int j = 0; j < 8; j++){ c_m[j] = cm[lane*8 + j]; c_u[j] = cu[lane*8 + j]; }
    for (int rr = 0; rr < 64; rr++){
      int d = w8*64 + rr;
      const float4* fr = (const float4*)(fcw + (size_t)d * DD + lane*8);
      float4 wA = fr[0], wB = fr[1];
      float xm = wA.x*c_m[0] + wA.y*c_m[1] + wA.z*c_m[2] + wA.w*c_m[3]
               + wB.x*c_m[4] + wB.y*c_m[5] + wB.z*c_m[6] + wB.w*c_m[7];
      float xu = wA.x*c_u[0] + wA.y*c_u[1] + wA.z*c_u[2] + wA.w*c_u[3]
               + wB.x*c_u[4] + wB.y*c_u[5] + wB.z*c_u[6] + wB.w*c_u[7];
      #pragma unroll
      for (int o = 1; o < 64; o <<= 1){ xm += __shfl_xor(xm, o, 64); xu += __shfl_xor(xu, o, 64); }
      if (lane == 0){
        float fb = fcb[d];
        a_m[(size_t)b*DD + d] = xm + fb;
        a_u[(size_t)b*DD + d] = xu + fb;
      }
    }
  }
}

// ---------------- K2: fused per-row chain, 64 rows/block, 16 waves, register GEMMs ----
__global__ __launch_bounds__(1024, 4) void k_main(
    const float* __restrict__ inp, const int* __restrict__ mask,
    const u16* __restrict__ lnm_g, const u16* __restrict__ lnm_b,
    const u16* __restrict__ w1,   const u16* __restrict__ b1,
    const u16* __restrict__ w2,   const u16* __restrict__ b2,
    const u16* __restrict__ lpc_w, const u16* __restrict__ lpc_b,
    const u16* __restrict__ lnc_g, const u16* __restrict__ lnc_b,
    const u16* __restrict__ pwf_w, const u16* __restrict__ pwf_b,
    const u16* __restrict__ lpi_w, const u16* __restrict__ lpi_b,
    const u16* __restrict__ lni_g, const u16* __restrict__ lni_b,
    const u16* __restrict__ lnf_g, const u16* __restrict__ lnf_b,
    const u16* __restrict__ mlpf_w, const u16* __restrict__ mlpf_b,
    const float* __restrict__ a_m, const float* __restrict__ a_u,
    float* __restrict__ out)
{
  __shared__ __align__(16) u16 A[64][LDA];   // GEMM A operand / LN outputs (~65KB)
  __shared__ __align__(16) u16 O[64][LDA];   // x staging, GEMM outputs / pre-LN staging
  __shared__ int marr[64];

  const int tid  = threadIdx.x;
  const int lane = tid & 63, wid = tid >> 6;  // 16 waves
  const int m = lane & 15, q = lane >> 4;
  const int r0 = blockIdx.x * 64;
  const int lrow = tid >> 4, lc = tid & 15;   // LN pass: 1024 thr = 64 rows x 16

  // ---- load 64 inp rows (f32 -> bf16) into O ----
  {
    if (tid < 64) marr[tid] = mask[r0 + tid];
    float4 va[4], vb[4];
    #pragma unroll
    for (int c = 0; c < 4; c++){
      int e = c*8192 + tid*8;                 // element index in [0, 32768)
      int row = e >> 9, col = e & 511;
      const float4* p = (const float4*)(inp + (size_t)(r0 + row) * DD + col);
      va[c] = p[0]; vb[c] = p[1];
    }
    #pragma unroll
    for (int c = 0; c < 4; c++){
      int e = c*8192 + tid*8;
      int row = e >> 9, col = e & 511;
      uint4 o;
      o.x = (u32)f2b(va[c].x) | ((u32)f2b(va[c].y) << 16);
      o.y = (u32)f2b(va[c].z) | ((u32)f2b(va[c].w) << 16);
      o.z = (u32)f2b(vb[c].x) | ((u32)f2b(vb[c].y) << 16);
      o.w = (u32)f2b(vb[c].z) | ((u32)f2b(vb[c].w) << 16);
      *(uint4*)&O[row][col] = o;
    }
  }
  __syncthreads();

  // ---- LN1 (torch LN): mha = LN(a_sel + x) -> A ; capture x into regs (packed bf16) ----
  u32 xp[16];
  {
    int Rg = r0 + lrow;
    int bi = Rg / SS;
    const float* asel = (marr[lrow] ? a_m : a_u) + (size_t)bi * DD;
    float v[32]; float s = 0.f;
    #pragma unroll
    for (int j = 0; j < 32; j++){
      int col = lc + j*16;
      u16 xu = O[lrow][col];
      if ((j & 1) == 0) xp[j >> 1] = (u32)xu;
      else              xp[j >> 1] |= ((u32)xu << 16);
      float x = asel[col] + b2f(xu);
      v[j] = x; s += x;
    }
    s = rsum16(s);
    float mean = s * (1.0f/512.0f);
    float vs = 0.f;
    #pragma unroll
    for (int j = 0; j < 32; j++){ float d = v[j] - mean; vs += d*d; }
    vs = rsum16(vs);
    float inv = 1.0f / sqrtf(vs * (1.0f/512.0f) + 1e-5f);
    #pragma unroll
    for (int j = 0; j < 32; j++){
      int col = lc + j*16;
      float r = b2f(lnm_g[col]) * (v[j] - mean) * inv + b2f(lnm_b[col]);
      A[lrow][col] = f2b(r);
    }
  }
  __syncthreads();

  // ---- GEMM1: h1 = relu(mha @ w1^T + b1) -> O[:,0:256]   (NT=1) ----
  {
    v4f acc[4][1];
    #pragma unroll
    for (int mt = 0; mt < 4; mt++) acc[mt][0] = (v4f){0.f,0.f,0.f,0.f};
    mm64<512,1>(A, w1, wid, lane, m, q, acc);
    int col = wid*16 + m;
    float bias = b2f(b1[col]);
    #pragma unroll
    for (int mt = 0; mt < 4; mt++)
      #pragma unroll
      for (int i = 0; i < 4; i++){
        float val = acc[mt][0][i] + bias;
        O[mt*16 + q*4 + i][col] = f2b(val > 0.f ? val : 0.f);
      }
  }
  __syncthreads();

  // ---- GEMM2: ffn = h1 @ w2^T + b2 ; (ffn + mha residual) -> O   (NT=2, K=256) ----
  {
    v4f acc[4][2];
    #pragma unroll
    for (int mt = 0; mt < 4; mt++)
      #pragma unroll
      for (int j = 0; j < 2; j++) acc[mt][j] = (v4f){0.f,0.f,0.f,0.f};
    mm64<256,2>(O, w2, wid, lane, m, q, acc);
    __syncthreads();   // all reads of h1 from O done
    #pragma unroll
    for (int j = 0; j < 2; j++){
      int col = (wid + 16*j)*16 + m;
      float bias = b2f(b2[col]);
      #pragma unroll
      for (int mt = 0; mt < 4; mt++)
        #pragma unroll
        for (int i = 0; i < 4; i++){
          int row = mt*16 + q*4 + i;
          O[row][col] = f2b(acc[mt][j][i] + bias + b2f(A[row][col]));  // + mha residual
        }
    }
  }
  __syncthreads();

  // ---- LN2 (custom, lni): ctx2 = LNc(ffn+mha); y = ctx2 + x -> A ----
  ln_custom_pass<true>(lrow, lc, O, A, xp, lni_g, lni_b);
  __syncthreads();

  // ---- GEMM3: z = y @ lpc_w^T + 2*lpc_b -> O   (NT=2, K=512) ----
  {
    v4f acc[4][2];
    #pragma unroll
    for (int mt = 0; mt < 4; mt++)
      #pragma unroll
      for (int j = 0; j < 2; j++) acc[mt][j] = (v4f){0.f,0.f,0.f,0.f};
    mm64<512,2>(A, lpc_w, wid, lane, m, q, acc);
    #pragma unroll
    for (int j = 0; j < 2; j++){
      int col = (wid + 16*j)*16 + m;
      float bias = 2.0f * b2f(lpc_b[col]);
      #pragma unroll
      for (int mt = 0; mt < 4; mt++)
        #pragma unroll
        for (int i = 0; i < 4; i++) O[mt*16 + q*4 + i][col] = f2b(acc[mt][j][i] + bias);
    }
  }
  __syncthreads();

  // ---- LN3 (custom, lnc): res_inp = LNc(z) -> A ----
  ln_custom_pass<false>(lrow, lc, O, A, nullptr, lnc_g, lnc_b);
  __syncthreads();

  // ---- GEMM4: h2 = relu(res_inp @ pwf^T + pwf_b) -> O[:,0:256]  (NT=1) ----
  {
    v4f acc[4][1];
    #pragma unroll
    for (int mt = 0; mt < 4; mt++) acc[mt][0] = (v4f){0.f,0.f,0.f,0.f};
    mm64<512,1>(A, pwf_w, wid, lane, m, q, acc);
    int col = wid*16 + m;
    float bias = b2f(pwf_b[col]);
    #pragma unroll
    for (int mt = 0; mt < 4; mt++)
      #pragma unroll
      for (int i = 0; i < 4; i++){
        float val = acc[mt][0][i] + bias;
        O[mt*16 + q*4 + i][col] = f2b(val > 0.f ? val : 0.f);
      }
  }
  __syncthreads();

  // ---- GEMM5: rv = h2 @ lpi^T + lpi_b ; (rv + res_inp residual) -> O  (NT=2, K=256) ----
  {
    v4f acc[4][2];
    #pragma unroll
    for (int mt = 0; mt < 4; mt++)
      #pragma unroll
      for (int j = 0; j < 2; j++) acc[mt][j] = (v4f){0.f,0.f,0.f,0.f};
    mm64<256,2>(O, lpi_w, wid, lane, m, q, acc);
    __syncthreads();   // all reads of h2 from O done
    #pragma unroll
    for (int j = 0; j < 2; j++){
      int col = (wid + 16*j)*16 + m;
      float bias = b2f(lpi_b[col]);
      #pragma unroll
      for (int mt = 0; mt < 4; mt++)
        #pragma unroll
        for (int i = 0; i < 4; i++){
          int row = mt*16 + q*4 + i;
          O[row][col] = f2b(acc[mt][j][i] + bias + b2f(A[row][col]));  // + res_inp residual
        }
    }
  }
  __syncthreads();

  // ---- LN4 (custom, lnf): res = LNc(rv+res_inp) -> A ----
  ln_custom_pass<false>(lrow, lc, O, A, nullptr, lnf_g, lnf_b);
  __syncthreads();

  // ---- GEMM6: out = res @ mlpf^T + mlpf_b  (packed 256 cols, zeros >=230, NT=1) ----
  {
    v4f acc[4][1];
    #pragma unroll
    for (int mt = 0; mt < 4; mt++) acc[mt][0] = (v4f){0.f,0.f,0.f,0.f};
    mm64<512,1>(A, mlpf_w, wid, lane, m, q, acc);
    int col = wid*16 + m;
    if (col < HIDN){
      float bias = b2f(mlpf_b[col]);
      #pragma unroll
      for (int mt = 0; mt < 4; mt++)
        #pragma unroll
        for (int i = 0; i < 4; i++){
          int row = mt*16 + q*4 + i;
          out[(size_t)(r0 + row)*HIDN + col] = acc[mt][0][i] + bias;   // float32 output
        }
    }
  }
}

extern "C" void kernel_launch(void* const* d_in, const int* in_sizes, int n_in,
                              void* d_out, int out_size, void* d_ws, size_t ws_size,
                              hipStream_t stream)
{
  const float* inp    = (const float*)d_in[0];
  const int*   mask   = (const int*)d_in[1];
  // d_in[2] = gate: dead computation in the reference
  const float* wv     = (const float*)d_in[3];
  const float* bv     = (const float*)d_in[4];
  const float* fc_w   = (const float*)d_in[5];
  const float* fc_b   = (const float*)d_in[6];

  // ws layout: a_m f32[512*512] | a_u f32[512*512] | bf16 packed weights/vectors
  float* a_m = (float*)d_ws;
  float* a_u = a_m + (size_t)BB * DD;
  u16* bfb = (u16*)((char*)d_ws + 2u * BB * DD * sizeof(float));

  // packed bf16 region offsets (elements)
  const int OW1   = 0;                       // 256x512 packed
  const int OW2   = OW1   + DFF*DD;          // 512x256 packed
  const int OLPC  = OW2   + DD*DFF;          // 512x512 packed
  const int OPWF  = OLPC  + DD*DD;           // 256x512 packed
  const int OLPI  = OPWF  + DFF*DD;          // 512x256 packed
  const int OMLPF = OLPI  + DD*DFF;          // 256x512 packed (cols >=230 zero)
  int voff = OMLPF + 256*DD;
  const int OLNMG = voff; voff += DD;
  const int OLNMB = voff; voff += DD;
  const int OB1   = voff; voff += DFF;
  const int OB2   = voff; voff += DD;
  const int OLPCB = voff; voff += DD;
  const int OLNCG = voff; voff += DD;
  const int OLNCB = voff; voff += DD;
  const int OPWFB = voff; voff += DFF;
  const int OLPIB = voff; voff += DD;
  const int OLNIG = voff; voff += DD;
  const int OLNIB = voff; voff += DD;
  const int OLNFG = voff; voff += DD;
  const int OLNFB = voff; voff += DD;
  const int OMLPFB = voff; voff += HIDN;

  CvtArgs ca;
  const int srcidx[NSEG] = {9, 11, 13, 17, 19, 25,      // w1,w2,lpc_w,pwf_w,lpi_w,mlpf_w
                            7, 8, 10, 12, 14, 15, 16, 18, 20, 21, 22, 23, 24, 26};
  const int offs[NSEG]   = {OW1, OW2, OLPC, OPWF, OLPI, OMLPF,
                            OLNMG, OLNMB, OB1, OB2, OLPCB, OLNCG, OLNCB, OPWFB,
                            OLPIB, OLNIG, OLNIB, OLNFG, OLNFB, OMLPFB};
  const int lens[NSEG]   = {DFF*DD, DD*DFF, DD*DD, DFF*DD, DD*DFF, 256*DD,
                            DD, DD, DFF, DD, DD, DD, DD, DFF, DD, DD, DD, DD, DD, HIDN};
  const int ncss[6] = {4, 3, 4, 4, 3, 4};        // log2(K/32): K=512 -> 4, K=256 -> 3
  const int nins[6] = {DFF, DD, DD, DFF, DD, HIDN};
  for (int i = 0; i < NSEG; i++){
    ca.src[i] = (const float*)d_in[srcidx[i]];
    ca.off[i] = offs[i];
    ca.n[i]   = lens[i];
  }
  for (int i = 0; i < 6; i++){ ca.ncs[i] = ncss[i]; ca.nin[i] = nins[i]; }
  ca.dst = bfb;

  k_pre<<<BB, 512, 0, stream>>>(ca, inp, mask, wv, bv, fc_w, fc_b, a_m, a_u);
  k_main<<<(BB*SS)/64, 1024, 0, stream>>>(inp, mask,
      bfb + OLNMG, bfb + OLNMB,
      bfb + OW1,   bfb + OB1,
      bfb + OW2,   bfb + OB2,
      bfb + OLPC,  bfb + OLPCB,
      bfb + OLNCG, bfb + OLNCB,
      bfb + OPWF,  bfb + OPWFB,
      bfb + OLPI,  bfb + OLPIB,
      bfb + OLNIG, bfb + OLNIB,
      bfb + OLNFG, bfb + OLNFB,
      bfb + OMLPF, bfb + OMLPFB,
      a_m, a_u, (float*)d_out);
}